// Round 4
// baseline (152.861 us; speedup 1.0000x reference)
//
#include <hip/hip_runtime.h>

#define B_SZ 8192
#define D_SZ 4096

// ws float layout (R = row-chunks):
//   partials [0, R*8*D)        partial[(r*8+seg)*D + col]
//     seg: 0=mean_all 1=mean_c1 2=lsd_all 3=lsd_c1 4=z_all 5=z_c1 6=z2_all 7=z2_c1
//   scalars  at SC=R*8*D       [0]=cnt1 [1]=logdet_all [2]=logdet_c1 [3]=pad
//   dslots   at SC+4 (doubles) 64 slots x {S0,S1,L0,L1}  (written unconditionally)

// Single block: no atomics, plain stores of the 3 scalar sums.
__global__ __launch_bounds__(256)
void count_logdet_kernel(const int* __restrict__ target,
                         const float* __restrict__ logdet,
                         float* __restrict__ sc) {
    __shared__ float red[3][4];
    float c = 0.f, a = 0.f, o = 0.f;
#pragma unroll
    for (int i = threadIdx.x * 4; i < B_SZ; i += 1024) {
        const int4   t = *(const int4*)(target + i);
        const float4 l = *(const float4*)(logdet + i);
        const float m0 = (t.x == 1) ? 1.f : 0.f;
        const float m1 = (t.y == 1) ? 1.f : 0.f;
        const float m2 = (t.z == 1) ? 1.f : 0.f;
        const float m3 = (t.w == 1) ? 1.f : 0.f;
        c += m0 + m1 + m2 + m3;                       // exact: integer-valued
        a += l.x + l.y + l.z + l.w;
        o += l.x * m0 + l.y * m1 + l.z * m2 + l.w * m3;
    }
    for (int off = 32; off > 0; off >>= 1) {
        c += __shfl_down(c, off);
        a += __shfl_down(a, off);
        o += __shfl_down(o, off);
    }
    const int w = threadIdx.x >> 6;
    if ((threadIdx.x & 63) == 0) { red[0][w] = c; red[1][w] = a; red[2][w] = o; }
    __syncthreads();
    if (threadIdx.x == 0) {
        sc[0] = red[0][0] + red[0][1] + red[0][2] + red[0][3];
        sc[1] = red[1][0] + red[1][1] + red[1][2] + red[1][3];
        sc[2] = red[2][0] + red[2][1] + red[2][2] + red[2][3];
    }
}

// Stage 1: masked column partial-sums, no atomics, 8-deep load batches for MLP.
// grid = (D/1024, R, 3); blockIdx.z: 0=mean, 1=log_sd, 2=z (+z^2).
template <int ROWS_PER>
__global__ __launch_bounds__(256, 4)   // VGPR cap 128: room for 8 float4 buffers
void colsum_kernel(const float* __restrict__ z,
                   const float* __restrict__ mean,
                   const float* __restrict__ lsd,
                   const int* __restrict__ target,
                   float* __restrict__ ws) {
    const int col = blockIdx.x * 1024 + (threadIdx.x << 2);
    const int i0  = blockIdx.y * ROWS_PER;
    float* pbase  = ws + (size_t)blockIdx.y * (8 * D_SZ);

#define LOAD_BATCH(arr)                                                        \
    float4 v[8];                                                               \
    {                                                                          \
        const float* b = (arr) + (size_t)i * D_SZ + col;                       \
        _Pragma("unroll")                                                      \
        for (int k = 0; k < 8; ++k) v[k] = *(const float4*)(b + (size_t)k * D_SZ); \
    }                                                                          \
    float mk[8];                                                               \
    {                                                                          \
        const int4 ta = *(const int4*)(target + i);                            \
        const int4 tb = *(const int4*)(target + i + 4);                        \
        mk[0] = (ta.x == 1) ? 1.f : 0.f; mk[1] = (ta.y == 1) ? 1.f : 0.f;      \
        mk[2] = (ta.z == 1) ? 1.f : 0.f; mk[3] = (ta.w == 1) ? 1.f : 0.f;      \
        mk[4] = (tb.x == 1) ? 1.f : 0.f; mk[5] = (tb.y == 1) ? 1.f : 0.f;      \
        mk[6] = (tb.z == 1) ? 1.f : 0.f; mk[7] = (tb.w == 1) ? 1.f : 0.f;      \
    }

    if (blockIdx.z == 2) {
        float4 aA = {0,0,0,0}, a1 = {0,0,0,0};
        float4 qA = {0,0,0,0}, q1 = {0,0,0,0};
        for (int i = i0; i < i0 + ROWS_PER; i += 8) {
            LOAD_BATCH(z)
#pragma unroll
            for (int k = 0; k < 8; ++k) {
                const float4 vv = v[k];
                const float  m  = mk[k];
                aA.x += vv.x; aA.y += vv.y; aA.z += vv.z; aA.w += vv.w;
                a1.x = fmaf(vv.x, m, a1.x); a1.y = fmaf(vv.y, m, a1.y);
                a1.z = fmaf(vv.z, m, a1.z); a1.w = fmaf(vv.w, m, a1.w);
                const float qx = vv.x*vv.x, qy = vv.y*vv.y;
                const float qz = vv.z*vv.z, qw = vv.w*vv.w;
                qA.x += qx; qA.y += qy; qA.z += qz; qA.w += qw;
                q1.x = fmaf(qx, m, q1.x); q1.y = fmaf(qy, m, q1.y);
                q1.z = fmaf(qz, m, q1.z); q1.w = fmaf(qw, m, q1.w);
            }
        }
        *(float4*)(pbase + 4 * D_SZ + col) = aA;
        *(float4*)(pbase + 5 * D_SZ + col) = a1;
        *(float4*)(pbase + 6 * D_SZ + col) = qA;
        *(float4*)(pbase + 7 * D_SZ + col) = q1;
    } else {
        const float* arr = blockIdx.z ? lsd : mean;
        const int segbase = blockIdx.z * 2;
        float4 aA = {0,0,0,0}, a1 = {0,0,0,0};
        for (int i = i0; i < i0 + ROWS_PER; i += 8) {
            LOAD_BATCH(arr)
#pragma unroll
            for (int k = 0; k < 8; ++k) {
                const float4 vv = v[k];
                const float  m  = mk[k];
                aA.x += vv.x; aA.y += vv.y; aA.z += vv.z; aA.w += vv.w;
                a1.x = fmaf(vv.x, m, a1.x); a1.y = fmaf(vv.y, m, a1.y);
                a1.z = fmaf(vv.z, m, a1.z); a1.w = fmaf(vv.w, m, a1.w);
            }
        }
        *(float4*)(pbase + (segbase + 0) * D_SZ + col) = aA;
        *(float4*)(pbase + (segbase + 1) * D_SZ + col) = a1;
    }
#undef LOAD_BATCH
}

// Stage 2 (fused): per column d, reduce R partials, write mu/lsd outputs,
// per-wave double partial sums to dslots (no atomics, no init needed).
__global__ __launch_bounds__(256)
void finalize_cols_kernel(const float* __restrict__ part, int R,
                          const float* __restrict__ sc,
                          double* __restrict__ dslots,
                          float* __restrict__ out) {
    const int d = blockIdx.x * 256 + threadIdx.x;
    float ma = 0, m1 = 0, la = 0, l1 = 0, za = 0, z1 = 0, qa = 0, q1 = 0;
#pragma unroll 4
    for (int r = 0; r < R; ++r) {
        const float* p = part + (size_t)r * (8 * D_SZ) + d;
        ma += p[0 * D_SZ]; m1 += p[1 * D_SZ];
        la += p[2 * D_SZ]; l1 += p[3 * D_SZ];
        za += p[4 * D_SZ]; z1 += p[5 * D_SZ];
        qa += p[6 * D_SZ]; q1 += p[7 * D_SZ];
    }
    const float cnt1 = sc[0];
    const float cnt0 = (float)B_SZ - cnt1;

    const float mu1 = m1 / cnt1, mu0 = (ma - m1) / cnt0;
    const float ls1 = l1 / cnt1, ls0 = (la - l1) / cnt0;

    // outputs: [0]=prior, [1,1+2D)=mus (class-major), [1+2D,1+4D)=lsds, [1+4D..]=lp
    out[1 + d]            = mu0;
    out[1 + D_SZ + d]     = mu1;
    out[1 + 2 * D_SZ + d] = ls0;
    out[1 + 3 * D_SZ + d] = ls1;

    const float z0 = za - z1, q0 = qa - q1;
    const double w0 = 0.5 * exp(-2.0 * (double)ls0);
    const double w1 = 0.5 * exp(-2.0 * (double)ls1);
    // sum_{i in c} (z - mu)^2 = Q_c - 2 mu_c Z_c + cnt_c mu_c^2
    double S0 = w0 * ((double)q0 - 2.0 * (double)mu0 * (double)z0 + (double)cnt0 * (double)mu0 * (double)mu0);
    double S1 = w1 * ((double)q1 - 2.0 * (double)mu1 * (double)z1 + (double)cnt1 * (double)mu1 * (double)mu1);
    double L0 = (double)ls0;
    double L1 = (double)ls1;

    for (int off = 32; off > 0; off >>= 1) {
        S0 += __shfl_down(S0, off);
        S1 += __shfl_down(S1, off);
        L0 += __shfl_down(L0, off);
        L1 += __shfl_down(L1, off);
    }
    if ((threadIdx.x & 63) == 0) {
        double* wd = dslots + (blockIdx.x * 4 + (threadIdx.x >> 6)) * 4;
        wd[0] = S0; wd[1] = S1; wd[2] = L0; wd[3] = L1;
    }
}

// One wave sums the 64 dslots and emits the scalar outputs.
__global__ void finalize_scalars_kernel(const float* __restrict__ sc,
                                        const double* __restrict__ dslots,
                                        float* __restrict__ out) {
    const double* p = dslots + threadIdx.x * 4;   // exactly 64 slots
    double S0 = p[0], S1 = p[1], L0 = p[2], L1 = p[3];
    for (int off = 32; off > 0; off >>= 1) {
        S0 += __shfl_down(S0, off);
        S1 += __shfl_down(S1, off);
        L0 += __shfl_down(L0, off);
        L1 += __shfl_down(L1, off);
    }
    if (threadIdx.x == 0) {
        const double LOG2PI = 1.8378770664093453;
        const double cnt1 = (double)sc[0];
        const double cnt0 = (double)B_SZ - cnt1;
        const double ldm1 = (double)sc[2] / cnt1;
        const double ldm0 = ((double)sc[1] - (double)sc[2]) / cnt0;

        const double c0 = -0.5 * LOG2PI * (double)D_SZ - L0;
        const double c1 = -0.5 * LOG2PI * (double)D_SZ - L1;
        const double lp0 = c0 - S0 / cnt0;
        const double lp1 = c1 - S1 / cnt1;

        out[1 + 4 * D_SZ + 0] = (float)lp0;
        out[1 + 4 * D_SZ + 1] = (float)lp1;
        out[0] = (float)(0.5 * ((lp0 + ldm0) + (lp1 + ldm1)));
    }
}

extern "C" void kernel_launch(void* const* d_in, const int* in_sizes, int n_in,
                              void* d_out, int out_size, void* d_ws, size_t ws_size,
                              hipStream_t stream) {
    const float* z      = (const float*)d_in[0];
    const float* mean   = (const float*)d_in[1];
    const float* log_sd = (const float*)d_in[2];
    const int*   target = (const int*)d_in[3];
    const float* logdet = (const float*)d_in[4];
    float* out = (float*)d_out;
    float* ws  = (float*)d_ws;

    // Largest R whose partials + tail fit in ws.
    int R = 64;
    while (R > 8) {
        const size_t need = ((size_t)R * 8 * D_SZ + 4) * 4 + 64 * 4 * 8;
        if (need <= ws_size) break;
        R >>= 1;
    }
    float*  sc     = ws + (size_t)R * 8 * D_SZ;
    double* dslots = (double*)(sc + 4);

    count_logdet_kernel<<<1, 256, 0, stream>>>(target, logdet, sc);

    const dim3 grid(D_SZ / 1024, R, 3);
    switch (R) {
        case 64: colsum_kernel<B_SZ/64><<<grid, 256, 0, stream>>>(z, mean, log_sd, target, ws); break;
        case 32: colsum_kernel<B_SZ/32><<<grid, 256, 0, stream>>>(z, mean, log_sd, target, ws); break;
        case 16: colsum_kernel<B_SZ/16><<<grid, 256, 0, stream>>>(z, mean, log_sd, target, ws); break;
        default: colsum_kernel<B_SZ/8 ><<<grid, 256, 0, stream>>>(z, mean, log_sd, target, ws); break;
    }

    finalize_cols_kernel<<<D_SZ / 256, 256, 0, stream>>>(ws, R, sc, dslots, out);
    finalize_scalars_kernel<<<1, 64, 0, stream>>>(sc, dslots, out);
}

// Round 5
// 152.371 us; speedup vs baseline: 1.0032x; 1.0032x over previous
//
#include <hip/hip_runtime.h>

#define B_SZ 8192
#define D_SZ 4096

// ws float layout (P = row-chunks per array):
//   pmean [P][2][D]   at 0            segs: 0=all 1=class1
//   plsd  [P][2][D]   at P*2*D
//   pz    [P][4][D]   at P*4*D        segs: 0=z_all 1=z_c1 2=z2_all 3=z2_c1
//   red   [8][D]      at P*8*D        0=m_all 1=m_c1 2=l_all 3=l_c1 4=z_all 5=z_c1 6=q_all 7=q_c1
//   scpart[8][4]      at P*8*D+8*D    per-count-block {cnt1, ld_all, ld_c1, pad}
//   dslots (doubles)  after scpart    64 x {S0,S1,L0,L1}

// 8 blocks x 256 thr, each thread exactly 4 elements; no atomics, no memset.
__global__ __launch_bounds__(256)
void count_logdet_kernel(const int* __restrict__ target,
                         const float* __restrict__ logdet,
                         float* __restrict__ scpart) {
    __shared__ float red[3][4];
    const int i = (blockIdx.x * 256 + threadIdx.x) * 4;
    const int4   t = *(const int4*)(target + i);
    const float4 l = *(const float4*)(logdet + i);
    const float m0 = (t.x == 1) ? 1.f : 0.f;
    const float m1 = (t.y == 1) ? 1.f : 0.f;
    const float m2 = (t.z == 1) ? 1.f : 0.f;
    const float m3 = (t.w == 1) ? 1.f : 0.f;
    float c = m0 + m1 + m2 + m3;                      // exact: integer-valued
    float a = l.x + l.y + l.z + l.w;
    float o = l.x * m0 + l.y * m1 + l.z * m2 + l.w * m3;
    for (int off = 32; off > 0; off >>= 1) {
        c += __shfl_down(c, off);
        a += __shfl_down(a, off);
        o += __shfl_down(o, off);
    }
    const int w = threadIdx.x >> 6;
    if ((threadIdx.x & 63) == 0) { red[0][w] = c; red[1][w] = a; red[2][w] = o; }
    __syncthreads();
    if (threadIdx.x == 0) {
        scpart[blockIdx.x * 4 + 0] = red[0][0] + red[0][1] + red[0][2] + red[0][3];
        scpart[blockIdx.x * 4 + 1] = red[1][0] + red[1][1] + red[1][2] + red[1][3];
        scpart[blockIdx.x * 4 + 2] = red[2][0] + red[2][1] + red[2][2] + red[2][3];
    }
}

// Stage 1: 1024-thread block spans the FULL 4096-col row -> each block is a
// perfectly sequential stream (16 KB/row-iteration, consecutive rows).
// grid = (P, 3); blockIdx.y: 0=mean, 1=log_sd, 2=z (+z^2). No atomics.
__global__ __launch_bounds__(1024, 8)   // 2 blocks/CU, VGPR cap 64
void colsum_kernel(const float* __restrict__ z,
                   const float* __restrict__ mean,
                   const float* __restrict__ lsd,
                   const int* __restrict__ target,
                   float* __restrict__ pmean,
                   float* __restrict__ plsd,
                   float* __restrict__ pz,
                   int rows_per) {
    const int col = threadIdx.x << 2;
    const int i0  = blockIdx.x * rows_per;

    if (blockIdx.y == 2) {
        float4 aA = {0,0,0,0}, a1 = {0,0,0,0};
        float4 qA = {0,0,0,0}, q1 = {0,0,0,0};
        for (int i = i0; i < i0 + rows_per; i += 2) {
            const float4 va = *(const float4*)(z + (size_t)i * D_SZ + col);
            const float4 vb = *(const float4*)(z + ((size_t)i + 1) * D_SZ + col);
            const int2   t  = *(const int2*)(target + i);
            const float ma = (t.x == 1) ? 1.f : 0.f;
            const float mb = (t.y == 1) ? 1.f : 0.f;

            aA.x += va.x; aA.y += va.y; aA.z += va.z; aA.w += va.w;
            a1.x = fmaf(va.x, ma, a1.x); a1.y = fmaf(va.y, ma, a1.y);
            a1.z = fmaf(va.z, ma, a1.z); a1.w = fmaf(va.w, ma, a1.w);
            float qx = va.x*va.x, qy = va.y*va.y, qz = va.z*va.z, qw = va.w*va.w;
            qA.x += qx; qA.y += qy; qA.z += qz; qA.w += qw;
            q1.x = fmaf(qx, ma, q1.x); q1.y = fmaf(qy, ma, q1.y);
            q1.z = fmaf(qz, ma, q1.z); q1.w = fmaf(qw, ma, q1.w);

            aA.x += vb.x; aA.y += vb.y; aA.z += vb.z; aA.w += vb.w;
            a1.x = fmaf(vb.x, mb, a1.x); a1.y = fmaf(vb.y, mb, a1.y);
            a1.z = fmaf(vb.z, mb, a1.z); a1.w = fmaf(vb.w, mb, a1.w);
            qx = vb.x*vb.x; qy = vb.y*vb.y; qz = vb.z*vb.z; qw = vb.w*vb.w;
            qA.x += qx; qA.y += qy; qA.z += qz; qA.w += qw;
            q1.x = fmaf(qx, mb, q1.x); q1.y = fmaf(qy, mb, q1.y);
            q1.z = fmaf(qz, mb, q1.z); q1.w = fmaf(qw, mb, q1.w);
        }
        float* pb = pz + (size_t)blockIdx.x * (4 * D_SZ);
        *(float4*)(pb + 0 * D_SZ + col) = aA;
        *(float4*)(pb + 1 * D_SZ + col) = a1;
        *(float4*)(pb + 2 * D_SZ + col) = qA;
        *(float4*)(pb + 3 * D_SZ + col) = q1;
    } else {
        const float* arr = blockIdx.y ? lsd : mean;
        float* pb = (blockIdx.y ? plsd : pmean) + (size_t)blockIdx.x * (2 * D_SZ);
        float4 aA = {0,0,0,0}, a1 = {0,0,0,0};
        for (int i = i0; i < i0 + rows_per; i += 2) {
            const float4 va = *(const float4*)(arr + (size_t)i * D_SZ + col);
            const float4 vb = *(const float4*)(arr + ((size_t)i + 1) * D_SZ + col);
            const int2   t  = *(const int2*)(target + i);
            const float ma = (t.x == 1) ? 1.f : 0.f;
            const float mb = (t.y == 1) ? 1.f : 0.f;

            aA.x += va.x; aA.y += va.y; aA.z += va.z; aA.w += va.w;
            a1.x = fmaf(va.x, ma, a1.x); a1.y = fmaf(va.y, ma, a1.y);
            a1.z = fmaf(va.z, ma, a1.z); a1.w = fmaf(va.w, ma, a1.w);

            aA.x += vb.x; aA.y += vb.y; aA.z += vb.z; aA.w += vb.w;
            a1.x = fmaf(vb.x, mb, a1.x); a1.y = fmaf(vb.y, mb, a1.y);
            a1.z = fmaf(vb.z, mb, a1.z); a1.w = fmaf(vb.w, mb, a1.w);
        }
        *(float4*)(pb + 0 * D_SZ + col) = aA;
        *(float4*)(pb + 1 * D_SZ + col) = a1;
    }
}

// Stage 2: reduce partials over chunks. One thread per (seg,col); partials are
// L2/L3-hot (just written). grid = 8*D/256 = 128 blocks.
__global__ __launch_bounds__(256)
void reduce_partials_kernel(const float* __restrict__ pmean,
                            const float* __restrict__ plsd,
                            const float* __restrict__ pz,
                            float* __restrict__ red, int P) {
    const int s   = blockIdx.x * 256 + threadIdx.x;
    const int seg = s >> 12;            // D = 4096
    const int d   = s & (D_SZ - 1);
    const float* base;
    int stride;
    if (seg < 2)      { base = pmean + (size_t)seg       * D_SZ + d; stride = 2 * D_SZ; }
    else if (seg < 4) { base = plsd  + (size_t)(seg - 2) * D_SZ + d; stride = 2 * D_SZ; }
    else              { base = pz    + (size_t)(seg - 4) * D_SZ + d; stride = 4 * D_SZ; }
    float acc = 0.f;
    for (int c = 0; c < P; ++c) acc += base[(size_t)c * stride];
    red[s] = acc;
}

// Per column d: write mu/lsd outputs, per-wave double partials (no atomics).
__global__ __launch_bounds__(256)
void finalize_cols_kernel(const float* __restrict__ red,
                          const float* __restrict__ scpart,
                          double* __restrict__ dslots,
                          float* __restrict__ out) {
    const int d = blockIdx.x * 256 + threadIdx.x;
    float cnt1 = 0.f;
#pragma unroll
    for (int b = 0; b < 8; ++b) cnt1 += scpart[b * 4];
    const float cnt0 = (float)B_SZ - cnt1;

    const float ma = red[0 * D_SZ + d], m1 = red[1 * D_SZ + d];
    const float la = red[2 * D_SZ + d], l1 = red[3 * D_SZ + d];
    const float za = red[4 * D_SZ + d], z1 = red[5 * D_SZ + d];
    const float qa = red[6 * D_SZ + d], q1 = red[7 * D_SZ + d];

    const float mu1 = m1 / cnt1, mu0 = (ma - m1) / cnt0;
    const float ls1 = l1 / cnt1, ls0 = (la - l1) / cnt0;

    // outputs: [0]=prior, [1,1+2D)=mus (class-major), [1+2D,1+4D)=lsds, [1+4D..]=lp
    out[1 + d]            = mu0;
    out[1 + D_SZ + d]     = mu1;
    out[1 + 2 * D_SZ + d] = ls0;
    out[1 + 3 * D_SZ + d] = ls1;

    const float z0 = za - z1, q0 = qa - q1;
    const double w0 = 0.5 * exp(-2.0 * (double)ls0);
    const double w1 = 0.5 * exp(-2.0 * (double)ls1);
    // sum_{i in c} (z - mu)^2 = Q_c - 2 mu_c Z_c + cnt_c mu_c^2
    double S0 = w0 * ((double)q0 - 2.0 * (double)mu0 * (double)z0 + (double)cnt0 * (double)mu0 * (double)mu0);
    double S1 = w1 * ((double)q1 - 2.0 * (double)mu1 * (double)z1 + (double)cnt1 * (double)mu1 * (double)mu1);
    double L0 = (double)ls0;
    double L1 = (double)ls1;

    for (int off = 32; off > 0; off >>= 1) {
        S0 += __shfl_down(S0, off);
        S1 += __shfl_down(S1, off);
        L0 += __shfl_down(L0, off);
        L1 += __shfl_down(L1, off);
    }
    if ((threadIdx.x & 63) == 0) {
        double* wd = dslots + (blockIdx.x * 4 + (threadIdx.x >> 6)) * 4;
        wd[0] = S0; wd[1] = S1; wd[2] = L0; wd[3] = L1;
    }
}

// One wave sums the 64 dslots + 8 scalar partials, emits scalar outputs.
__global__ void finalize_scalars_kernel(const float* __restrict__ scpart,
                                        const double* __restrict__ dslots,
                                        float* __restrict__ out) {
    const double* p = dslots + threadIdx.x * 4;
    double S0 = p[0], S1 = p[1], L0 = p[2], L1 = p[3];
    for (int off = 32; off > 0; off >>= 1) {
        S0 += __shfl_down(S0, off);
        S1 += __shfl_down(S1, off);
        L0 += __shfl_down(L0, off);
        L1 += __shfl_down(L1, off);
    }
    if (threadIdx.x == 0) {
        float cnt1f = 0.f, lda = 0.f, ld1 = 0.f;
        for (int b = 0; b < 8; ++b) {
            cnt1f += scpart[b * 4 + 0];
            lda   += scpart[b * 4 + 1];
            ld1   += scpart[b * 4 + 2];
        }
        const double LOG2PI = 1.8378770664093453;
        const double cnt1 = (double)cnt1f;
        const double cnt0 = (double)B_SZ - cnt1;
        const double ldm1 = (double)ld1 / cnt1;
        const double ldm0 = ((double)lda - (double)ld1) / cnt0;

        const double c0 = -0.5 * LOG2PI * (double)D_SZ - L0;
        const double c1 = -0.5 * LOG2PI * (double)D_SZ - L1;
        const double lp0 = c0 - S0 / cnt0;
        const double lp1 = c1 - S1 / cnt1;

        out[1 + 4 * D_SZ + 0] = (float)lp0;
        out[1 + 4 * D_SZ + 1] = (float)lp1;
        out[0] = (float)(0.5 * ((lp0 + ldm0) + (lp1 + ldm1)));
    }
}

extern "C" void kernel_launch(void* const* d_in, const int* in_sizes, int n_in,
                              void* d_out, int out_size, void* d_ws, size_t ws_size,
                              hipStream_t stream) {
    const float* z      = (const float*)d_in[0];
    const float* mean   = (const float*)d_in[1];
    const float* log_sd = (const float*)d_in[2];
    const int*   target = (const int*)d_in[3];
    const float* logdet = (const float*)d_in[4];
    float* out = (float*)d_out;
    float* ws  = (float*)d_ws;

    // Largest P whose partials + tail fit in ws.
    int P = 256;
    while (P > 32) {
        const size_t need = ((size_t)P * 8 * D_SZ + 8 * D_SZ + 32) * 4 + 64 * 4 * 8;
        if (need <= ws_size) break;
        P >>= 1;
    }
    const int rows_per = B_SZ / P;
    float* pmean = ws;
    float* plsd  = ws + (size_t)P * 2 * D_SZ;
    float* pz    = ws + (size_t)P * 4 * D_SZ;
    float* red   = ws + (size_t)P * 8 * D_SZ;
    float* scpart = red + 8 * D_SZ;
    double* dslots = (double*)(scpart + 32);

    const dim3 grid(P, 3);
    colsum_kernel<<<grid, 1024, 0, stream>>>(z, mean, log_sd, target,
                                             pmean, plsd, pz, rows_per);
    count_logdet_kernel<<<8, 256, 0, stream>>>(target, logdet, scpart);
    reduce_partials_kernel<<<8 * D_SZ / 256, 256, 0, stream>>>(pmean, plsd, pz, red, P);
    finalize_cols_kernel<<<D_SZ / 256, 256, 0, stream>>>(red, scpart, dslots, out);
    finalize_scalars_kernel<<<1, 64, 0, stream>>>(scpart, dslots, out);
}

// Round 6
// 103.726 us; speedup vs baseline: 1.4737x; 1.4690x over previous
//
#include <hip/hip_runtime.h>

#define B_SZ 8192
#define D_SZ 4096

// ws float layout (P = row-chunks, template):
//   part [8][P][D]  at 0         seg: 0=m_all 1=m_c1 2=l_all 3=l_c1 4=z_all 5=z_c1 6=q_all 7=q_c1
//   red  [2][8][D]  at 8*P*D     (two halves of the P-reduction)
//   scpart [8][4]   after red    per-count-block {cnt1, ld_all, ld_c1, pad}
//   dslots          after scpart 64 x {S0,S1,L0,L1} doubles

// 8 blocks x 256 thr, each thread exactly 4 elements; plain stores, no memset.
__global__ __launch_bounds__(256)
void count_logdet_kernel(const int* __restrict__ target,
                         const float* __restrict__ logdet,
                         float* __restrict__ scpart) {
    __shared__ float red[3][4];
    const int i = (blockIdx.x * 256 + threadIdx.x) * 4;
    const int4   t = *(const int4*)(target + i);
    const float4 l = *(const float4*)(logdet + i);
    const float m0 = (t.x == 1) ? 1.f : 0.f;
    const float m1 = (t.y == 1) ? 1.f : 0.f;
    const float m2 = (t.z == 1) ? 1.f : 0.f;
    const float m3 = (t.w == 1) ? 1.f : 0.f;
    float c = m0 + m1 + m2 + m3;                      // exact: integer-valued
    float a = l.x + l.y + l.z + l.w;
    float o = l.x * m0 + l.y * m1 + l.z * m2 + l.w * m3;
    for (int off = 32; off > 0; off >>= 1) {
        c += __shfl_down(c, off);
        a += __shfl_down(a, off);
        o += __shfl_down(o, off);
    }
    const int w = threadIdx.x >> 6;
    if ((threadIdx.x & 63) == 0) { red[0][w] = c; red[1][w] = a; red[2][w] = o; }
    __syncthreads();
    if (threadIdx.x == 0) {
        scpart[blockIdx.x * 4 + 0] = red[0][0] + red[0][1] + red[0][2] + red[0][3];
        scpart[blockIdx.x * 4 + 1] = red[1][0] + red[1][1] + red[1][2] + red[1][3];
        scpart[blockIdx.x * 4 + 2] = red[2][0] + red[2][1] + red[2][2] + red[2][3];
    }
}

// Stage 1 (R1 geometry + float4 + 2-row unroll + interleaved 3-array streams).
// grid = (D/1024, PC), block 256; thread owns 4 cols; 6 independent float4
// loads in flight per iteration. Partials stored, no atomics.
template <int PC>
__global__ __launch_bounds__(256, 4)   // VGPR cap 128: keep ~70 live regs
void colsum_kernel(const float* __restrict__ z,
                   const float* __restrict__ mean,
                   const float* __restrict__ lsd,
                   const int* __restrict__ target,
                   float* __restrict__ part) {
    constexpr int RP = B_SZ / PC;
    const int col = blockIdx.x * 1024 + (threadIdx.x << 2);
    const int r   = blockIdx.y;
    const int i0  = r * RP;

    float4 mA = {0,0,0,0}, m1 = {0,0,0,0};
    float4 lA = {0,0,0,0}, l1 = {0,0,0,0};
    float4 zA = {0,0,0,0}, z1 = {0,0,0,0};
    float4 qA = {0,0,0,0}, q1 = {0,0,0,0};

    for (int i = i0; i < i0 + RP; i += 2) {
        const size_t b0 = (size_t)i * D_SZ + col;
        const size_t b1 = b0 + D_SZ;
        // issue all 6 loads up front -> 6 outstanding 1KB wave-loads
        const float4 vza = *(const float4*)(z    + b0);
        const float4 vzb = *(const float4*)(z    + b1);
        const float4 vma = *(const float4*)(mean + b0);
        const float4 vmb = *(const float4*)(mean + b1);
        const float4 vla = *(const float4*)(lsd  + b0);
        const float4 vlb = *(const float4*)(lsd  + b1);
        const int2   t   = *(const int2*)(target + i);
        const float ka = (t.x == 1) ? 1.f : 0.f;
        const float kb = (t.y == 1) ? 1.f : 0.f;

        mA.x += vma.x; mA.y += vma.y; mA.z += vma.z; mA.w += vma.w;
        m1.x = fmaf(vma.x, ka, m1.x); m1.y = fmaf(vma.y, ka, m1.y);
        m1.z = fmaf(vma.z, ka, m1.z); m1.w = fmaf(vma.w, ka, m1.w);
        mA.x += vmb.x; mA.y += vmb.y; mA.z += vmb.z; mA.w += vmb.w;
        m1.x = fmaf(vmb.x, kb, m1.x); m1.y = fmaf(vmb.y, kb, m1.y);
        m1.z = fmaf(vmb.z, kb, m1.z); m1.w = fmaf(vmb.w, kb, m1.w);

        lA.x += vla.x; lA.y += vla.y; lA.z += vla.z; lA.w += vla.w;
        l1.x = fmaf(vla.x, ka, l1.x); l1.y = fmaf(vla.y, ka, l1.y);
        l1.z = fmaf(vla.z, ka, l1.z); l1.w = fmaf(vla.w, ka, l1.w);
        lA.x += vlb.x; lA.y += vlb.y; lA.z += vlb.z; lA.w += vlb.w;
        l1.x = fmaf(vlb.x, kb, l1.x); l1.y = fmaf(vlb.y, kb, l1.y);
        l1.z = fmaf(vlb.z, kb, l1.z); l1.w = fmaf(vlb.w, kb, l1.w);

        zA.x += vza.x; zA.y += vza.y; zA.z += vza.z; zA.w += vza.w;
        z1.x = fmaf(vza.x, ka, z1.x); z1.y = fmaf(vza.y, ka, z1.y);
        z1.z = fmaf(vza.z, ka, z1.z); z1.w = fmaf(vza.w, ka, z1.w);
        float qx = vza.x*vza.x, qy = vza.y*vza.y, qz = vza.z*vza.z, qw = vza.w*vza.w;
        qA.x += qx; qA.y += qy; qA.z += qz; qA.w += qw;
        q1.x = fmaf(qx, ka, q1.x); q1.y = fmaf(qy, ka, q1.y);
        q1.z = fmaf(qz, ka, q1.z); q1.w = fmaf(qw, ka, q1.w);

        zA.x += vzb.x; zA.y += vzb.y; zA.z += vzb.z; zA.w += vzb.w;
        z1.x = fmaf(vzb.x, kb, z1.x); z1.y = fmaf(vzb.y, kb, z1.y);
        z1.z = fmaf(vzb.z, kb, z1.z); z1.w = fmaf(vzb.w, kb, z1.w);
        qx = vzb.x*vzb.x; qy = vzb.y*vzb.y; qz = vzb.z*vzb.z; qw = vzb.w*vzb.w;
        qA.x += qx; qA.y += qy; qA.z += qz; qA.w += qw;
        q1.x = fmaf(qx, kb, q1.x); q1.y = fmaf(qy, kb, q1.y);
        q1.z = fmaf(qz, kb, q1.z); q1.w = fmaf(qw, kb, q1.w);
    }

    // part[seg][r][D], coalesced float4 stores
    *(float4*)(part + ((size_t)(0 * PC + r)) * D_SZ + col) = mA;
    *(float4*)(part + ((size_t)(1 * PC + r)) * D_SZ + col) = m1;
    *(float4*)(part + ((size_t)(2 * PC + r)) * D_SZ + col) = lA;
    *(float4*)(part + ((size_t)(3 * PC + r)) * D_SZ + col) = l1;
    *(float4*)(part + ((size_t)(4 * PC + r)) * D_SZ + col) = zA;
    *(float4*)(part + ((size_t)(5 * PC + r)) * D_SZ + col) = z1;
    *(float4*)(part + ((size_t)(6 * PC + r)) * D_SZ + col) = qA;
    *(float4*)(part + ((size_t)(7 * PC + r)) * D_SZ + col) = q1;
}

// Stage 2: reduce partials over r. grid = (8 segs, 4 col-chunks, 2 halves),
// block 256, float4 -> 1KB coalesced wave reads, partials L2/L3-hot.
__global__ __launch_bounds__(256)
void reduce_partials_kernel(const float* __restrict__ part,
                            float* __restrict__ red, int P) {
    const int seg = blockIdx.x, chunk = blockIdx.y, half = blockIdx.z;
    const int col = chunk * 1024 + (threadIdx.x << 2);
    const int r0  = half * (P >> 1);
    float4 acc = {0,0,0,0};
    for (int r = r0; r < r0 + (P >> 1); ++r) {
        const float4 v = *(const float4*)(part + ((size_t)seg * P + r) * D_SZ + col);
        acc.x += v.x; acc.y += v.y; acc.z += v.z; acc.w += v.w;
    }
    *(float4*)(red + ((size_t)(half * 8 + seg)) * D_SZ + col) = acc;
}

// Per column d: combine halves, write mu/lsd outputs, per-wave double partials.
__global__ __launch_bounds__(256)
void finalize_cols_kernel(const float* __restrict__ red,
                          const float* __restrict__ scpart,
                          double* __restrict__ dslots,
                          float* __restrict__ out) {
    const int d = blockIdx.x * 256 + threadIdx.x;
    float cnt1 = 0.f;
#pragma unroll
    for (int b = 0; b < 8; ++b) cnt1 += scpart[b * 4];
    const float cnt0 = (float)B_SZ - cnt1;

#define RSEG(s) (red[(s) * D_SZ + d] + red[(8 + (s)) * D_SZ + d])
    const float ma = RSEG(0), m1 = RSEG(1);
    const float la = RSEG(2), l1 = RSEG(3);
    const float za = RSEG(4), z1 = RSEG(5);
    const float qa = RSEG(6), q1 = RSEG(7);
#undef RSEG

    const float mu1 = m1 / cnt1, mu0 = (ma - m1) / cnt0;
    const float ls1 = l1 / cnt1, ls0 = (la - l1) / cnt0;

    // outputs: [0]=prior, [1,1+2D)=mus (class-major), [1+2D,1+4D)=lsds, [1+4D..]=lp
    out[1 + d]            = mu0;
    out[1 + D_SZ + d]     = mu1;
    out[1 + 2 * D_SZ + d] = ls0;
    out[1 + 3 * D_SZ + d] = ls1;

    const float z0 = za - z1, q0 = qa - q1;
    const double w0 = 0.5 * exp(-2.0 * (double)ls0);
    const double w1 = 0.5 * exp(-2.0 * (double)ls1);
    // sum_{i in c} (z - mu)^2 = Q_c - 2 mu_c Z_c + cnt_c mu_c^2
    double S0 = w0 * ((double)q0 - 2.0 * (double)mu0 * (double)z0 + (double)cnt0 * (double)mu0 * (double)mu0);
    double S1 = w1 * ((double)q1 - 2.0 * (double)mu1 * (double)z1 + (double)cnt1 * (double)mu1 * (double)mu1);
    double L0 = (double)ls0;
    double L1 = (double)ls1;

    for (int off = 32; off > 0; off >>= 1) {
        S0 += __shfl_down(S0, off);
        S1 += __shfl_down(S1, off);
        L0 += __shfl_down(L0, off);
        L1 += __shfl_down(L1, off);
    }
    if ((threadIdx.x & 63) == 0) {
        double* wd = dslots + (blockIdx.x * 4 + (threadIdx.x >> 6)) * 4;
        wd[0] = S0; wd[1] = S1; wd[2] = L0; wd[3] = L1;
    }
}

// One wave sums the 64 dslots + 8 scalar partials, emits scalar outputs.
__global__ void finalize_scalars_kernel(const float* __restrict__ scpart,
                                        const double* __restrict__ dslots,
                                        float* __restrict__ out) {
    const double* p = dslots + threadIdx.x * 4;
    double S0 = p[0], S1 = p[1], L0 = p[2], L1 = p[3];
    for (int off = 32; off > 0; off >>= 1) {
        S0 += __shfl_down(S0, off);
        S1 += __shfl_down(S1, off);
        L0 += __shfl_down(L0, off);
        L1 += __shfl_down(L1, off);
    }
    if (threadIdx.x == 0) {
        float cnt1f = 0.f, lda = 0.f, ld1 = 0.f;
        for (int b = 0; b < 8; ++b) {
            cnt1f += scpart[b * 4 + 0];
            lda   += scpart[b * 4 + 1];
            ld1   += scpart[b * 4 + 2];
        }
        const double LOG2PI = 1.8378770664093453;
        const double cnt1 = (double)cnt1f;
        const double cnt0 = (double)B_SZ - cnt1;
        const double ldm1 = (double)ld1 / cnt1;
        const double ldm0 = ((double)lda - (double)ld1) / cnt0;

        const double c0 = -0.5 * LOG2PI * (double)D_SZ - L0;
        const double c1 = -0.5 * LOG2PI * (double)D_SZ - L1;
        const double lp0 = c0 - S0 / cnt0;
        const double lp1 = c1 - S1 / cnt1;

        out[1 + 4 * D_SZ + 0] = (float)lp0;
        out[1 + 4 * D_SZ + 1] = (float)lp1;
        out[0] = (float)(0.5 * ((lp0 + ldm0) + (lp1 + ldm1)));
    }
}

extern "C" void kernel_launch(void* const* d_in, const int* in_sizes, int n_in,
                              void* d_out, int out_size, void* d_ws, size_t ws_size,
                              hipStream_t stream) {
    const float* z      = (const float*)d_in[0];
    const float* mean   = (const float*)d_in[1];
    const float* log_sd = (const float*)d_in[2];
    const int*   target = (const int*)d_in[3];
    const float* logdet = (const float*)d_in[4];
    float* out = (float*)d_out;
    float* ws  = (float*)d_ws;

    // Largest P whose partials + tail fit in ws.
    int P = 128;
    while (P > 32) {
        const size_t need = ((size_t)P * 8 * D_SZ + 16 * D_SZ + 32) * 4 + 64 * 4 * 8;
        if (need <= ws_size) break;
        P >>= 1;
    }
    float*  part   = ws;
    float*  red    = ws + (size_t)P * 8 * D_SZ;
    float*  scpart = red + 16 * D_SZ;
    double* dslots = (double*)(scpart + 32);

    const dim3 grid(D_SZ / 1024, P);
    switch (P) {
        case 128: colsum_kernel<128><<<grid, 256, 0, stream>>>(z, mean, log_sd, target, part); break;
        case  64: colsum_kernel<64 ><<<grid, 256, 0, stream>>>(z, mean, log_sd, target, part); break;
        default:  colsum_kernel<32 ><<<grid, 256, 0, stream>>>(z, mean, log_sd, target, part); break;
    }
    count_logdet_kernel<<<8, 256, 0, stream>>>(target, logdet, scpart);

    reduce_partials_kernel<<<dim3(8, 4, 2), 256, 0, stream>>>(part, red, P);
    finalize_cols_kernel<<<D_SZ / 256, 256, 0, stream>>>(red, scpart, dslots, out);
    finalize_scalars_kernel<<<1, 64, 0, stream>>>(scpart, dslots, out);
}

// Round 7
// 88.511 us; speedup vs baseline: 1.7270x; 1.1719x over previous
//
#include <hip/hip_runtime.h>

#define B_SZ 8192
#define D_SZ 4096
#define PC   128            // row-chunks
#define RP   (B_SZ / PC)    // rows per chunk = 64

// ws float layout:
//   part [8][PC][D] at 0          seg: 0=m_all 1=m_c1 2=l_all 3=l_c1 4=z_all 5=z_c1 6=q_all 7=q_c1
//   red  [2][8][D]  at 8*PC*D     two halves of the PC-reduction
//   sc   [8]        after red     [0]=cnt1 [1]=ld_all [2]=ld_c1
//   dslots (dbl)    after sc      64 x {S0,S1,L0,L1}

__device__ __forceinline__ void acc4(float4& a, const float4 v) {
    a.x += v.x; a.y += v.y; a.z += v.z; a.w += v.w;
}
__device__ __forceinline__ void fma4(float4& a, const float4 v, const float k) {
    a.x = fmaf(v.x, k, a.x); a.y = fmaf(v.y, k, a.y);
    a.z = fmaf(v.z, k, a.z); a.w = fmaf(v.w, k, a.w);
}
__device__ __forceinline__ float4 sq4(const float4 v) {
    return {v.x * v.x, v.y * v.y, v.z * v.z, v.w * v.w};
}

// Stage 1: interleaved 3-array masked column sums, 4-row explicit load batch
// (12 float4 + 1 int4 in flight, pinned by sched_barrier). grid (4, PC).
__global__ __launch_bounds__(256, 4)
void colsum_kernel(const float* __restrict__ z,
                   const float* __restrict__ mean,
                   const float* __restrict__ lsd,
                   const int* __restrict__ target,
                   float* __restrict__ part) {
    const int col = blockIdx.x * 1024 + (threadIdx.x << 2);
    const int r   = blockIdx.y;
    const size_t base0 = (size_t)(r * RP) * D_SZ + col;

    const float* pz = z    + base0;
    const float* pm = mean + base0;
    const float* pl = lsd  + base0;
    const int*   pt = target + r * RP;

    float4 mA = {0,0,0,0}, m1 = {0,0,0,0};
    float4 lA = {0,0,0,0}, l1 = {0,0,0,0};
    float4 zA = {0,0,0,0}, z1 = {0,0,0,0};
    float4 qA = {0,0,0,0}, q1 = {0,0,0,0};

    for (int it = 0; it < RP / 4; ++it) {
        // --- 13 loads, distinct registers, no consumer in between ---
        const float4 vz0 = *(const float4*)(pz);
        const float4 vz1 = *(const float4*)(pz + 1 * D_SZ);
        const float4 vz2 = *(const float4*)(pz + 2 * D_SZ);
        const float4 vz3 = *(const float4*)(pz + 3 * D_SZ);
        const float4 vm0 = *(const float4*)(pm);
        const float4 vm1 = *(const float4*)(pm + 1 * D_SZ);
        const float4 vm2 = *(const float4*)(pm + 2 * D_SZ);
        const float4 vm3 = *(const float4*)(pm + 3 * D_SZ);
        const float4 vl0 = *(const float4*)(pl);
        const float4 vl1 = *(const float4*)(pl + 1 * D_SZ);
        const float4 vl2 = *(const float4*)(pl + 2 * D_SZ);
        const float4 vl3 = *(const float4*)(pl + 3 * D_SZ);
        const int4   t   = *(const int4*)(pt);
        __builtin_amdgcn_sched_barrier(0);   // loads may not sink past here

        const float k0 = (t.x == 1) ? 1.f : 0.f;
        const float k1 = (t.y == 1) ? 1.f : 0.f;
        const float k2 = (t.z == 1) ? 1.f : 0.f;
        const float k3 = (t.w == 1) ? 1.f : 0.f;

        acc4(mA, vm0); fma4(m1, vm0, k0);
        acc4(mA, vm1); fma4(m1, vm1, k1);
        acc4(mA, vm2); fma4(m1, vm2, k2);
        acc4(mA, vm3); fma4(m1, vm3, k3);

        acc4(lA, vl0); fma4(l1, vl0, k0);
        acc4(lA, vl1); fma4(l1, vl1, k1);
        acc4(lA, vl2); fma4(l1, vl2, k2);
        acc4(lA, vl3); fma4(l1, vl3, k3);

        acc4(zA, vz0); fma4(z1, vz0, k0);
        acc4(zA, vz1); fma4(z1, vz1, k1);
        acc4(zA, vz2); fma4(z1, vz2, k2);
        acc4(zA, vz3); fma4(z1, vz3, k3);

        const float4 q0 = sq4(vz0); acc4(qA, q0); fma4(q1, q0, k0);
        const float4 qq1 = sq4(vz1); acc4(qA, qq1); fma4(q1, qq1, k1);
        const float4 q2 = sq4(vz2); acc4(qA, q2); fma4(q1, q2, k2);
        const float4 q3 = sq4(vz3); acc4(qA, q3); fma4(q1, q3, k3);

        pz += 4 * D_SZ; pm += 4 * D_SZ; pl += 4 * D_SZ; pt += 4;
    }

    // part[seg][r][D], coalesced float4 stores
    *(float4*)(part + ((size_t)(0 * PC + r)) * D_SZ + col) = mA;
    *(float4*)(part + ((size_t)(1 * PC + r)) * D_SZ + col) = m1;
    *(float4*)(part + ((size_t)(2 * PC + r)) * D_SZ + col) = lA;
    *(float4*)(part + ((size_t)(3 * PC + r)) * D_SZ + col) = l1;
    *(float4*)(part + ((size_t)(4 * PC + r)) * D_SZ + col) = zA;
    *(float4*)(part + ((size_t)(5 * PC + r)) * D_SZ + col) = z1;
    *(float4*)(part + ((size_t)(6 * PC + r)) * D_SZ + col) = qA;
    *(float4*)(part + ((size_t)(7 * PC + r)) * D_SZ + col) = q1;
}

// Stage 2 (fused): blocks 0..63 reduce partials over r (L2/L3-hot);
// block 64 computes the target-count / logdet scalar sums. No atomics.
__global__ __launch_bounds__(256)
void reduce_count_kernel(const float* __restrict__ part,
                         const int* __restrict__ target,
                         const float* __restrict__ logdet,
                         float* __restrict__ red,
                         float* __restrict__ sc) {
    if (blockIdx.x == 64) {
        __shared__ float rsm[3][4];
        float c = 0.f, a = 0.f, o = 0.f;
#pragma unroll
        for (int k = 0; k < 8; ++k) {
            const int i = k * 1024 + (threadIdx.x << 2);
            const int4   t = *(const int4*)(target + i);
            const float4 l = *(const float4*)(logdet + i);
            const float n0 = (t.x == 1) ? 1.f : 0.f;
            const float n1 = (t.y == 1) ? 1.f : 0.f;
            const float n2 = (t.z == 1) ? 1.f : 0.f;
            const float n3 = (t.w == 1) ? 1.f : 0.f;
            c += n0 + n1 + n2 + n3;                   // exact: integer-valued
            a += l.x + l.y + l.z + l.w;
            o += l.x * n0 + l.y * n1 + l.z * n2 + l.w * n3;
        }
        for (int off = 32; off > 0; off >>= 1) {
            c += __shfl_down(c, off);
            a += __shfl_down(a, off);
            o += __shfl_down(o, off);
        }
        const int w = threadIdx.x >> 6;
        if ((threadIdx.x & 63) == 0) { rsm[0][w] = c; rsm[1][w] = a; rsm[2][w] = o; }
        __syncthreads();
        if (threadIdx.x == 0) {
            sc[0] = rsm[0][0] + rsm[0][1] + rsm[0][2] + rsm[0][3];
            sc[1] = rsm[1][0] + rsm[1][1] + rsm[1][2] + rsm[1][3];
            sc[2] = rsm[2][0] + rsm[2][1] + rsm[2][2] + rsm[2][3];
        }
        return;
    }
    const int seg = blockIdx.x >> 3;
    const int sub = blockIdx.x & 7;
    const int col = (sub >> 1) * 1024 + (threadIdx.x << 2);
    const int r0  = (sub & 1) * (PC / 2);
    float4 acc = {0,0,0,0};
    for (int r = r0; r < r0 + PC / 2; ++r) {
        const float4 v = *(const float4*)(part + ((size_t)seg * PC + r) * D_SZ + col);
        acc4(acc, v);
    }
    *(float4*)(red + ((size_t)((sub & 1) * 8 + seg)) * D_SZ + col) = acc;
}

// Per column d: combine halves, write mu/lsd outputs, per-wave double partials.
__global__ __launch_bounds__(256)
void finalize_cols_kernel(const float* __restrict__ red,
                          const float* __restrict__ sc,
                          double* __restrict__ dslots,
                          float* __restrict__ out) {
    const int d = blockIdx.x * 256 + threadIdx.x;
    const float cnt1 = sc[0];
    const float cnt0 = (float)B_SZ - cnt1;

#define RSEG(s) (red[(s) * D_SZ + d] + red[(8 + (s)) * D_SZ + d])
    const float ma = RSEG(0), m1 = RSEG(1);
    const float la = RSEG(2), l1 = RSEG(3);
    const float za = RSEG(4), z1 = RSEG(5);
    const float qa = RSEG(6), q1 = RSEG(7);
#undef RSEG

    const float mu1 = m1 / cnt1, mu0 = (ma - m1) / cnt0;
    const float ls1 = l1 / cnt1, ls0 = (la - l1) / cnt0;

    // outputs: [0]=prior, [1,1+2D)=mus (class-major), [1+2D,1+4D)=lsds, [1+4D..]=lp
    out[1 + d]            = mu0;
    out[1 + D_SZ + d]     = mu1;
    out[1 + 2 * D_SZ + d] = ls0;
    out[1 + 3 * D_SZ + d] = ls1;

    const float z0 = za - z1, q0 = qa - q1;
    const double w0 = 0.5 * exp(-2.0 * (double)ls0);
    const double w1 = 0.5 * exp(-2.0 * (double)ls1);
    // sum_{i in c} (z - mu)^2 = Q_c - 2 mu_c Z_c + cnt_c mu_c^2
    double S0 = w0 * ((double)q0 - 2.0 * (double)mu0 * (double)z0 + (double)cnt0 * (double)mu0 * (double)mu0);
    double S1 = w1 * ((double)q1 - 2.0 * (double)mu1 * (double)z1 + (double)cnt1 * (double)mu1 * (double)mu1);
    double L0 = (double)ls0;
    double L1 = (double)ls1;

    for (int off = 32; off > 0; off >>= 1) {
        S0 += __shfl_down(S0, off);
        S1 += __shfl_down(S1, off);
        L0 += __shfl_down(L0, off);
        L1 += __shfl_down(L1, off);
    }
    if ((threadIdx.x & 63) == 0) {
        double* wd = dslots + (blockIdx.x * 4 + (threadIdx.x >> 6)) * 4;
        wd[0] = S0; wd[1] = S1; wd[2] = L0; wd[3] = L1;
    }
}

// One wave sums the 64 dslots, emits scalar outputs.
__global__ void finalize_scalars_kernel(const float* __restrict__ sc,
                                        const double* __restrict__ dslots,
                                        float* __restrict__ out) {
    const double* p = dslots + threadIdx.x * 4;
    double S0 = p[0], S1 = p[1], L0 = p[2], L1 = p[3];
    for (int off = 32; off > 0; off >>= 1) {
        S0 += __shfl_down(S0, off);
        S1 += __shfl_down(S1, off);
        L0 += __shfl_down(L0, off);
        L1 += __shfl_down(L1, off);
    }
    if (threadIdx.x == 0) {
        const double LOG2PI = 1.8378770664093453;
        const double cnt1 = (double)sc[0];
        const double cnt0 = (double)B_SZ - cnt1;
        const double ldm1 = (double)sc[2] / cnt1;
        const double ldm0 = ((double)sc[1] - (double)sc[2]) / cnt0;

        const double c0 = -0.5 * LOG2PI * (double)D_SZ - L0;
        const double c1 = -0.5 * LOG2PI * (double)D_SZ - L1;
        const double lp0 = c0 - S0 / cnt0;
        const double lp1 = c1 - S1 / cnt1;

        out[1 + 4 * D_SZ + 0] = (float)lp0;
        out[1 + 4 * D_SZ + 1] = (float)lp1;
        out[0] = (float)(0.5 * ((lp0 + ldm0) + (lp1 + ldm1)));
    }
}

extern "C" void kernel_launch(void* const* d_in, const int* in_sizes, int n_in,
                              void* d_out, int out_size, void* d_ws, size_t ws_size,
                              hipStream_t stream) {
    const float* z      = (const float*)d_in[0];
    const float* mean   = (const float*)d_in[1];
    const float* log_sd = (const float*)d_in[2];
    const int*   target = (const int*)d_in[3];
    const float* logdet = (const float*)d_in[4];
    float* out = (float*)d_out;
    float* ws  = (float*)d_ws;

    float*  part   = ws;
    float*  red    = ws + (size_t)PC * 8 * D_SZ;
    float*  sc     = red + 16 * D_SZ;
    double* dslots = (double*)(sc + 8);

    colsum_kernel<<<dim3(D_SZ / 1024, PC), 256, 0, stream>>>(z, mean, log_sd, target, part);
    reduce_count_kernel<<<65, 256, 0, stream>>>(part, target, logdet, red, sc);
    finalize_cols_kernel<<<D_SZ / 256, 256, 0, stream>>>(red, sc, dslots, out);
    finalize_scalars_kernel<<<1, 64, 0, stream>>>(sc, dslots, out);
}